// Round 2
// baseline (1003.543 us; speedup 1.0000x reference)
//
#include <hip/hip_runtime.h>
#include <math.h>

#define BB 8
#define CC 512
#define KK 19
#define HWHW 16384
#define INV_HW (1.0f/16384.0f)

// -------- K1: mask = sigmoid(einsum('bchw,kc->bkhw', x, Wm) + bm) --------
// 512 blocks x 1024 threads. Block covers (b, 256-pixel chunk) over ALL 512 c.
// Threads split c 4 ways (cs = tid>>8, 128 c each) -> 16 waves/block for
// latency hiding; 2-stage fp32 LDS reduce combines the 4 partial pre_mask
// vectors, then cs==0 threads apply bias+sigmoid and store mask fp32.
__global__ __launch_bounds__(1024) void k_mask(const float* __restrict__ x,
                                               const float* __restrict__ Wm,
                                               const float* __restrict__ bm,
                                               float* __restrict__ mask) {
    const int blk = blockIdx.x;
    const int b = blk >> 6;
    const int slot = threadIdx.x & 255;
    const int cs = threadIdx.x >> 8;            // 0..3, owns c in [cs*128, cs*128+128)
    const int p = ((blk & 63) << 8) + slot;
    const float* xb = x + (size_t)b * CC * HWHW + p;
    const int c0 = cs << 7;

    float pm[KK];
#pragma unroll
    for (int k = 0; k < KK; ++k) pm[k] = 0.0f;

    for (int cc = 0; cc < 128; cc += 4) {
        const int c = c0 + cc;
        const float xv0 = xb[(size_t)(c + 0) * HWHW];
        const float xv1 = xb[(size_t)(c + 1) * HWHW];
        const float xv2 = xb[(size_t)(c + 2) * HWHW];
        const float xv3 = xb[(size_t)(c + 3) * HWHW];
#pragma unroll
        for (int k = 0; k < KK; ++k) {
            const float* wr = Wm + k * CC + c;   // uniform -> s_load
            pm[k] += wr[0] * xv0 + wr[1] * xv1 + wr[2] * xv2 + wr[3] * xv3;
        }
    }

    // 2-stage fp32 LDS reduce across the 4 c-split groups (40 KB LDS).
    __shared__ float red[2][256][KK + 1];
    if (cs >= 2) {
#pragma unroll
        for (int k = 0; k < KK; ++k) red[cs - 2][slot][k] = pm[k];
    }
    __syncthreads();
    if (cs < 2) {
#pragma unroll
        for (int k = 0; k < KK; ++k) pm[k] += red[cs][slot][k];
    }
    __syncthreads();
    if (cs == 1) {
#pragma unroll
        for (int k = 0; k < KK; ++k) red[0][slot][k] = pm[k];
    }
    __syncthreads();
    if (cs == 0) {
        float* mb = mask + (size_t)b * KK * HWHW + p;
#pragma unroll
        for (int k = 0; k < KK; ++k) {
            const float t = pm[k] + red[0][slot][k] + bm[k];
            mb[(size_t)k * HWHW] = 1.0f / (1.0f + __expf(-t));
        }
    }
}

// -------- K2: cf_part partials of class_feat = sum_p mask[b,k,p]*x[b,c,p] ----
// 8192 blocks: (b, c-quad, pixel-split sp of 8). Each block covers 2048 pixels,
// register-accumulates 19x4, shuffle+LDS reduces, writes 76 floats of partials.
__global__ __launch_bounds__(256) void k_classfeat(const float* __restrict__ x,
                                                   const float* __restrict__ mask,
                                                   float* __restrict__ cf_part) {
    const int blk = blockIdx.x;
    const int sp = blk & 7;
    const int cq = (blk >> 3) & 127;
    const int b = blk >> 10;
    const int c0 = cq << 2;
    const float* xb = x + (size_t)b * CC * HWHW;
    const float* mb = mask + (size_t)b * KK * HWHW;
    const int p0 = (sp << 11) + threadIdx.x;

    float acc[KK][4];
#pragma unroll
    for (int k = 0; k < KK; ++k)
#pragma unroll
        for (int j = 0; j < 4; ++j) acc[k][j] = 0.0f;

    for (int i = 0; i < 8; ++i) {
        const int p = p0 + (i << 8);
        const float xv0 = xb[(size_t)(c0 + 0) * HWHW + p];
        const float xv1 = xb[(size_t)(c0 + 1) * HWHW + p];
        const float xv2 = xb[(size_t)(c0 + 2) * HWHW + p];
        const float xv3 = xb[(size_t)(c0 + 3) * HWHW + p];
#pragma unroll
        for (int k = 0; k < KK; ++k) {
            const float m = mb[(size_t)k * HWHW + p];
            acc[k][0] += m * xv0;
            acc[k][1] += m * xv1;
            acc[k][2] += m * xv2;
            acc[k][3] += m * xv3;
        }
    }

    __shared__ float red[4][KK * 4];
    const int wave = threadIdx.x >> 6;
    const int lane = threadIdx.x & 63;
#pragma unroll
    for (int k = 0; k < KK; ++k)
#pragma unroll
        for (int j = 0; j < 4; ++j) {
            float v = acc[k][j];
#pragma unroll
            for (int off = 32; off > 0; off >>= 1) v += __shfl_down(v, off, 64);
            if (lane == 0) red[wave][k * 4 + j] = v;
        }
    __syncthreads();
    if (threadIdx.x < KK * 4) {
        const float s = red[0][threadIdx.x] + red[1][threadIdx.x] +
                        red[2][threadIdx.x] + red[3][threadIdx.x];
        cf_part[(((size_t)sp * BB + b) * 128 + cq) * (KK * 4) + threadIdx.x] = s;
    }
}

// -------- K2b: cf[b,k,c] = INV_HW * sum_sp cf_part --------
__global__ __launch_bounds__(256) void k_cf_reduce(const float* __restrict__ cf_part,
                                                   float* __restrict__ cf) {
    const int i = blockIdx.x * 256 + threadIdx.x;
    if (i >= BB * KK * CC) return;
    const int b = i / (KK * CC);
    const int r = i - b * (KK * CC);         // k*512 + c
    const int k = r >> 9;
    const int c = r & 511;
    const int cq = c >> 2;
    const int t = (k << 2) + (c & 3);
    float s = 0.0f;
#pragma unroll
    for (int sp = 0; sp < 8; ++sp)
        s += cf_part[(((size_t)sp * BB + b) * 128 + cq) * (KK * 4) + t];
    cf[i] = s * INV_HW;
}

// -------- K3: filters[b,k,o] = sum_c Wf[k,o,c]*cf[b,k,c] + bf[k,o] --------
__global__ __launch_bounds__(256) void k_filters(const float* __restrict__ Wf,
                                                 const float* __restrict__ bf,
                                                 const float* __restrict__ cf,
                                                 float* __restrict__ fil) {
    const int blk = blockIdx.x;
    const int k = blk >> 7;                         // 0..18
    const int o = ((blk & 127) << 2) + (threadIdx.x >> 6);
    const int lane = threadIdx.x & 63;
    const float* wrow = Wf + ((size_t)k * CC + o) * CC;

    float acc[BB];
#pragma unroll
    for (int b = 0; b < BB; ++b) acc[b] = 0.0f;

#pragma unroll
    for (int j = 0; j < CC / 64; ++j) {
        const int c = lane + (j << 6);
        const float wv = wrow[c];
#pragma unroll
        for (int b = 0; b < BB; ++b)
            acc[b] += wv * cf[((size_t)b * KK + k) * CC + c];
    }
#pragma unroll
    for (int b = 0; b < BB; ++b) {
#pragma unroll
        for (int off = 32; off > 0; off >>= 1)
            acc[b] += __shfl_down(acc[b], off, 64);
    }
    if (lane == 0) {
        const float bias = bf[k * CC + o];
#pragma unroll
        for (int b = 0; b < BB; ++b)
            fil[((size_t)b * KK + k) * CC + o] = acc[b] + bias;
    }
}

// -------- K4: pred[b,k,p] = sum_c filters[b,k,c]*x[b,c,p] --------
// Same structure as K1: 512 blocks x 1024 threads, in-block 4-way c-split,
// 2-stage LDS reduce, cs==0 stores the final output.
__global__ __launch_bounds__(1024) void k_pred(const float* __restrict__ x,
                                               const float* __restrict__ fil,
                                               float* __restrict__ out) {
    const int blk = blockIdx.x;
    const int b = blk >> 6;
    const int slot = threadIdx.x & 255;
    const int cs = threadIdx.x >> 8;
    const int p = ((blk & 63) << 8) + slot;
    const float* xb = x + (size_t)b * CC * HWHW + p;
    const float* fb = fil + (size_t)b * KK * CC;    // uniform base
    const int c0 = cs << 7;

    float acc[KK];
#pragma unroll
    for (int k = 0; k < KK; ++k) acc[k] = 0.0f;

    for (int cc = 0; cc < 128; cc += 4) {
        const int c = c0 + cc;
        const float xv0 = xb[(size_t)(c + 0) * HWHW];
        const float xv1 = xb[(size_t)(c + 1) * HWHW];
        const float xv2 = xb[(size_t)(c + 2) * HWHW];
        const float xv3 = xb[(size_t)(c + 3) * HWHW];
#pragma unroll
        for (int k = 0; k < KK; ++k) {
            const float* fr = fb + k * CC + c;       // uniform -> s_load
            acc[k] += fr[0] * xv0 + fr[1] * xv1 + fr[2] * xv2 + fr[3] * xv3;
        }
    }

    __shared__ float red[2][256][KK + 1];
    if (cs >= 2) {
#pragma unroll
        for (int k = 0; k < KK; ++k) red[cs - 2][slot][k] = acc[k];
    }
    __syncthreads();
    if (cs < 2) {
#pragma unroll
        for (int k = 0; k < KK; ++k) acc[k] += red[cs][slot][k];
    }
    __syncthreads();
    if (cs == 1) {
#pragma unroll
        for (int k = 0; k < KK; ++k) red[0][slot][k] = acc[k];
    }
    __syncthreads();
    if (cs == 0) {
        float* ob = out + (size_t)b * KK * HWHW + p;
#pragma unroll
        for (int k = 0; k < KK; ++k)
            ob[(size_t)k * HWHW] = acc[k] + red[0][slot][k];
    }
}

extern "C" void kernel_launch(void* const* d_in, const int* in_sizes, int n_in,
                              void* d_out, int out_size, void* d_ws, size_t ws_size,
                              hipStream_t stream) {
    const float* x  = (const float*)d_in[0];
    const float* Wm = (const float*)d_in[1];
    const float* bm = (const float*)d_in[2];
    const float* Wf = (const float*)d_in[3];
    const float* bf = (const float*)d_in[4];
    float* out = (float*)d_out;

    float* mask    = (float*)d_ws;                       // B*K*HW        (2,490,368)
    float* cf_part = mask + (size_t)BB * KK * HWHW;      // 8*B*128*76    (  622,592)
    float* cf      = cf_part + (size_t)8 * BB * 128 * (KK * 4);  // B*K*C (77,824)
    float* fil     = cf + (size_t)BB * KK * CC;          // B*K*C         (   77,824)

    k_mask<<<512, 1024, 0, stream>>>(x, Wm, bm, mask);
    k_classfeat<<<8192, 256, 0, stream>>>(x, mask, cf_part);
    k_cf_reduce<<<(BB * KK * CC + 255) / 256, 256, 0, stream>>>(cf_part, cf);
    k_filters<<<KK * 128, 256, 0, stream>>>(Wf, bf, cf, fil);
    k_pred<<<512, 1024, 0, stream>>>(x, fil, out);
}

// Round 3
// 476.208 us; speedup vs baseline: 2.1074x; 2.1074x over previous
//
#include <hip/hip_runtime.h>
#include <math.h>

#define BB 8
#define CC 512
#define KK 19
#define HWHW 16384
#define INV_HW (1.0f/16384.0f)

typedef __attribute__((ext_vector_type(8))) short bf16x8;
typedef __attribute__((ext_vector_type(4))) short s16x4;
typedef __attribute__((ext_vector_type(4))) float f32x4;

__device__ __forceinline__ unsigned short f2bf(float f) {
    unsigned int u = __float_as_uint(f);
    u = (u + 0x7fffu + ((u >> 16) & 1u)) >> 16;
    return (unsigned short)u;
}

// ================= k_s1: mask = sigmoid(Wm @ x + bm), bf16 out ==============
// 1024 blocks = (b=8) x (p-chunk=128 of 128 pixels). 256 thr (4 waves).
// Wm staged to LDS bf16 [20][512] (row19 zeroed), XOR-swizzled 16B chunks.
// x tile [64c][128p] transposed in-register to xt[p][c] bf16 per c-step.
__global__ __launch_bounds__(256) void k_s1(const float* __restrict__ x,
                                            const float* __restrict__ Wm,
                                            const float* __restrict__ bm,
                                            unsigned short* __restrict__ mask) {
    __shared__ short wm[20 * CC];
    __shared__ short xt[128 * 64];
    const int tid = threadIdx.x;
    const int b = blockIdx.x >> 7;
    const int p0 = (blockIdx.x & 127) << 7;
    const float* xb = x + ((size_t)b * CC) * HWHW + p0;

    for (int u = tid; u < 20 * 128; u += 256) {
        const int k = u >> 7;
        const int c4 = (u & 127) << 2;
        float4 w = {0.f, 0.f, 0.f, 0.f};
        if (k < KK) w = *(const float4*)(Wm + k * CC + c4);
        s16x4 v = { (short)f2bf(w.x), (short)f2bf(w.y), (short)f2bf(w.z), (short)f2bf(w.w) };
        *(s16x4*)&wm[(k << 9) + (((c4 >> 3) ^ (k & 7)) << 3) + (c4 & 7)] = v;
    }

    const int wv = tid >> 6, ln = tid & 63;
    const int lm = ln & 15, q = ln >> 4;
    const f32x4 zz = {0.f, 0.f, 0.f, 0.f};
    f32x4 acc[2][2];
    acc[0][0] = zz; acc[0][1] = zz; acc[1][0] = zz; acc[1][1] = zz;

    for (int cs = 0; cs < 8; ++cs) {
        __syncthreads();
#pragma unroll
        for (int r = 0; r < 2; ++r) {
            const int u = tid + (r << 8);
            const int cg = u >> 5;                 // 0..15, 4 c each
            const int p = (u & 31) << 2;           // 0..124
            const float* src = xb + (size_t)((cs << 6) + (cg << 2)) * HWHW + p;
            float4 F0 = *(const float4*)(src);
            float4 F1 = *(const float4*)(src + HWHW);
            float4 F2 = *(const float4*)(src + 2 * HWHW);
            float4 F3 = *(const float4*)(src + 3 * HWHW);
            const float* G0 = (const float*)&F0;
            const float* G1 = (const float*)&F1;
            const float* G2 = (const float*)&F2;
            const float* G3 = (const float*)&F3;
#pragma unroll
            for (int j = 0; j < 4; ++j) {
                const int pr = p + j;
                s16x4 v = { (short)f2bf(G0[j]), (short)f2bf(G1[j]),
                            (short)f2bf(G2[j]), (short)f2bf(G3[j]) };
                *(s16x4*)&xt[(pr << 6) + (((cg >> 1) ^ (pr & 7)) << 3) + ((cg & 1) << 2)] = v;
            }
        }
        __syncthreads();
#pragma unroll
        for (int ks = 0; ks < 2; ++ks) {
            const int gch = (cs << 3) + (ks << 2) + q;      // global c-chunk for A
            const int m1 = (lm < 3) ? (16 + lm) : 19;       // clamped pad row
            bf16x8 a0 = *(const bf16x8*)&wm[(lm << 9) + ((gch ^ (lm & 7)) << 3)];
            bf16x8 a1 = *(const bf16x8*)&wm[(m1 << 9) + ((gch ^ (m1 & 7)) << 3)];
            const int lch = (ks << 2) + q;
#pragma unroll
            for (int nt = 0; nt < 2; ++nt) {
                const int pr = (((wv << 1) + nt) << 4) + lm;
                bf16x8 bf_ = *(const bf16x8*)&xt[(pr << 6) + ((lch ^ (pr & 7)) << 3)];
                acc[0][nt] = __builtin_amdgcn_mfma_f32_16x16x32_bf16(a0, bf_, acc[0][nt], 0, 0, 0);
                acc[1][nt] = __builtin_amdgcn_mfma_f32_16x16x32_bf16(a1, bf_, acc[1][nt], 0, 0, 0);
            }
        }
    }

    unsigned short* mb = mask + ((size_t)b * KK) * HWHW + p0;
#pragma unroll
    for (int mt = 0; mt < 2; ++mt)
#pragma unroll
        for (int r = 0; r < 4; ++r) {
            const int k = (mt << 4) + (q << 2) + r;
            if (k < KK) {
                const float bias = bm[k];
#pragma unroll
                for (int nt = 0; nt < 2; ++nt) {
                    const int p = (((wv << 1) + nt) << 4) + lm;
                    const float t = acc[mt][nt][r] + bias;
                    mb[(size_t)k * HWHW + p] = f2bf(1.0f / (1.0f + __expf(-t)));
                }
            }
        }
}

// ====== k_s2: cf_part[s][b][k][c] = sum_{p in slice} mask[k][p]*x[c][p] =====
// K-dim = pixels: mask and x are both naturally contiguous along p.
// 1024 blocks = (b=8) x (c-tile=8 of 64) x (p-split=16 of 1024).
__global__ __launch_bounds__(256) void k_s2(const float* __restrict__ x,
                                            const unsigned short* __restrict__ mask,
                                            float* __restrict__ cf_part) {
    __shared__ short mt_[20 * 64];
    __shared__ short xtl[64 * 64];
    const int tid = threadIdx.x;
    const int s = blockIdx.x & 15;
    const int ct = (blockIdx.x >> 4) & 7;
    const int b = blockIdx.x >> 7;
    const int wv = tid >> 6, ln = tid & 63;
    const int lm = ln & 15, q = ln >> 4;
    const float* xb = x + ((size_t)b * CC + (ct << 6)) * HWHW + (s << 10);
    const unsigned short* mbs = mask + ((size_t)b * KK) * HWHW + (s << 10);

    const f32x4 zz = {0.f, 0.f, 0.f, 0.f};
    f32x4 acc[2];
    acc[0] = zz; acc[1] = zz;

    for (int kp = 0; kp < 16; ++kp) {
        __syncthreads();
        if (tid < 160) {                       // 20 rows x 8 chunks (row19 zero)
            const int k = tid >> 3, ch = tid & 7;
            uint4 v = {0u, 0u, 0u, 0u};
            if (k < KK) v = *(const uint4*)(mbs + (size_t)k * HWHW + (kp << 6) + (ch << 3));
            *(uint4*)&mt_[(k << 6) + ((ch ^ (k & 7)) << 3)] = v;
        }
#pragma unroll
        for (int r = 0; r < 4; ++r) {
            const int u = tid + (r << 8);
            const int c = u >> 4;               // 0..63
            const int pq = u & 15;              // p-quad
            float4 f = *(const float4*)(xb + (size_t)c * HWHW + (kp << 6) + (pq << 2));
            s16x4 v = { (short)f2bf(f.x), (short)f2bf(f.y), (short)f2bf(f.z), (short)f2bf(f.w) };
            *(s16x4*)&xtl[(c << 6) + (((pq >> 1) ^ (c & 7)) << 3) + ((pq & 1) << 2)] = v;
        }
        __syncthreads();
#pragma unroll
        for (int ks = 0; ks < 2; ++ks) {
            const int pch = (ks << 2) + q;      // local p-chunk
            const int cr = (wv << 4) + lm;      // this wave's c row
            bf16x8 bf_ = *(const bf16x8*)&xtl[(cr << 6) + ((pch ^ (cr & 7)) << 3)];
            const int m1 = (lm < 3) ? (16 + lm) : 19;
            bf16x8 a0 = *(const bf16x8*)&mt_[(lm << 6) + ((pch ^ (lm & 7)) << 3)];
            bf16x8 a1 = *(const bf16x8*)&mt_[(m1 << 6) + ((pch ^ (m1 & 7)) << 3)];
            acc[0] = __builtin_amdgcn_mfma_f32_16x16x32_bf16(a0, bf_, acc[0], 0, 0, 0);
            acc[1] = __builtin_amdgcn_mfma_f32_16x16x32_bf16(a1, bf_, acc[1], 0, 0, 0);
        }
    }

    float* dst = cf_part + ((size_t)(s * BB + b) * KK) * CC + (ct << 6) + (wv << 4) + lm;
#pragma unroll
    for (int mt = 0; mt < 2; ++mt)
#pragma unroll
        for (int r = 0; r < 4; ++r) {
            const int k = (mt << 4) + (q << 2) + r;
            if (k < KK) dst[(size_t)k * CC] = acc[mt][r];
        }
}

// ========== k_s2r: cf = INV_HW * sum_s cf_part ==========
__global__ __launch_bounds__(256) void k_s2r(const float* __restrict__ part,
                                             float* __restrict__ cf) {
    const int i = blockIdx.x * 256 + threadIdx.x;
    if (i >= BB * KK * CC) return;
    const int b = i / (KK * CC);
    const int rem = i - b * (KK * CC);
    float sum = 0.0f;
#pragma unroll
    for (int s = 0; s < 16; ++s)
        sum += part[((size_t)(s * BB + b) * KK) * CC + rem];
    cf[i] = sum * INV_HW;
}

// ====== k_filters: fil[b,k,o] = sum_c Wf[k,o,c]*cf[b,k,c] + bf[k,o] ======
__global__ __launch_bounds__(256) void k_filters(const float* __restrict__ Wf,
                                                 const float* __restrict__ bf,
                                                 const float* __restrict__ cf,
                                                 float* __restrict__ fil) {
    const int blk = blockIdx.x;
    const int k = blk >> 7;
    const int o = ((blk & 127) << 2) + (threadIdx.x >> 6);
    const int lane = threadIdx.x & 63;
    const float* wrow = Wf + ((size_t)k * CC + o) * CC;

    float acc[BB];
#pragma unroll
    for (int b = 0; b < BB; ++b) acc[b] = 0.0f;
#pragma unroll
    for (int j = 0; j < CC / 64; ++j) {
        const int c = lane + (j << 6);
        const float wv = wrow[c];
#pragma unroll
        for (int b = 0; b < BB; ++b)
            acc[b] += wv * cf[((size_t)b * KK + k) * CC + c];
    }
#pragma unroll
    for (int b = 0; b < BB; ++b) {
#pragma unroll
        for (int off = 32; off > 0; off >>= 1)
            acc[b] += __shfl_down(acc[b], off, 64);
    }
    if (lane == 0) {
        const float bias = bf[k * CC + o];
#pragma unroll
        for (int b = 0; b < BB; ++b)
            fil[((size_t)b * KK + k) * CC + o] = acc[b] + bias;
    }
}

// ================= k_s4: pred = fil[b] @ x, fp32 out ==============
__global__ __launch_bounds__(256) void k_s4(const float* __restrict__ x,
                                            const float* __restrict__ fil,
                                            float* __restrict__ out) {
    __shared__ short wm[20 * CC];
    __shared__ short xt[128 * 64];
    const int tid = threadIdx.x;
    const int b = blockIdx.x >> 7;
    const int p0 = (blockIdx.x & 127) << 7;
    const float* xb = x + ((size_t)b * CC) * HWHW + p0;
    const float* fb = fil + ((size_t)b * KK) * CC;

    for (int u = tid; u < 20 * 128; u += 256) {
        const int k = u >> 7;
        const int c4 = (u & 127) << 2;
        float4 w = {0.f, 0.f, 0.f, 0.f};
        if (k < KK) w = *(const float4*)(fb + k * CC + c4);
        s16x4 v = { (short)f2bf(w.x), (short)f2bf(w.y), (short)f2bf(w.z), (short)f2bf(w.w) };
        *(s16x4*)&wm[(k << 9) + (((c4 >> 3) ^ (k & 7)) << 3) + (c4 & 7)] = v;
    }

    const int wv = tid >> 6, ln = tid & 63;
    const int lm = ln & 15, q = ln >> 4;
    const f32x4 zz = {0.f, 0.f, 0.f, 0.f};
    f32x4 acc[2][2];
    acc[0][0] = zz; acc[0][1] = zz; acc[1][0] = zz; acc[1][1] = zz;

    for (int cs = 0; cs < 8; ++cs) {
        __syncthreads();
#pragma unroll
        for (int r = 0; r < 2; ++r) {
            const int u = tid + (r << 8);
            const int cg = u >> 5;
            const int p = (u & 31) << 2;
            const float* src = xb + (size_t)((cs << 6) + (cg << 2)) * HWHW + p;
            float4 F0 = *(const float4*)(src);
            float4 F1 = *(const float4*)(src + HWHW);
            float4 F2 = *(const float4*)(src + 2 * HWHW);
            float4 F3 = *(const float4*)(src + 3 * HWHW);
            const float* G0 = (const float*)&F0;
            const float* G1 = (const float*)&F1;
            const float* G2 = (const float*)&F2;
            const float* G3 = (const float*)&F3;
#pragma unroll
            for (int j = 0; j < 4; ++j) {
                const int pr = p + j;
                s16x4 v = { (short)f2bf(G0[j]), (short)f2bf(G1[j]),
                            (short)f2bf(G2[j]), (short)f2bf(G3[j]) };
                *(s16x4*)&xt[(pr << 6) + (((cg >> 1) ^ (pr & 7)) << 3) + ((cg & 1) << 2)] = v;
            }
        }
        __syncthreads();
#pragma unroll
        for (int ks = 0; ks < 2; ++ks) {
            const int gch = (cs << 3) + (ks << 2) + q;
            const int m1 = (lm < 3) ? (16 + lm) : 19;
            bf16x8 a0 = *(const bf16x8*)&wm[(lm << 9) + ((gch ^ (lm & 7)) << 3)];
            bf16x8 a1 = *(const bf16x8*)&wm[(m1 << 9) + ((gch ^ (m1 & 7)) << 3)];
            const int lch = (ks << 2) + q;
#pragma unroll
            for (int nt = 0; nt < 2; ++nt) {
                const int pr = (((wv << 1) + nt) << 4) + lm;
                bf16x8 bf_ = *(const bf16x8*)&xt[(pr << 6) + ((lch ^ (pr & 7)) << 3)];
                acc[0][nt] = __builtin_amdgcn_mfma_f32_16x16x32_bf16(a0, bf_, acc[0][nt], 0, 0, 0);
                acc[1][nt] = __builtin_amdgcn_mfma_f32_16x16x32_bf16(a1, bf_, acc[1][nt], 0, 0, 0);
            }
        }
    }

    float* ob = out + ((size_t)b * KK) * HWHW + p0;
#pragma unroll
    for (int mt = 0; mt < 2; ++mt)
#pragma unroll
        for (int r = 0; r < 4; ++r) {
            const int k = (mt << 4) + (q << 2) + r;
            if (k < KK) {
#pragma unroll
                for (int nt = 0; nt < 2; ++nt) {
                    const int p = (((wv << 1) + nt) << 4) + lm;
                    ob[(size_t)k * HWHW + p] = acc[mt][nt][r];
                }
            }
        }
}

extern "C" void kernel_launch(void* const* d_in, const int* in_sizes, int n_in,
                              void* d_out, int out_size, void* d_ws, size_t ws_size,
                              hipStream_t stream) {
    const float* x  = (const float*)d_in[0];
    const float* Wm = (const float*)d_in[1];
    const float* bm = (const float*)d_in[2];
    const float* Wf = (const float*)d_in[3];
    const float* bf = (const float*)d_in[4];
    float* out = (float*)d_out;

    unsigned short* mask = (unsigned short*)d_ws;                       // 4.98 MB bf16
    float* cf_part = (float*)((char*)d_ws + (size_t)BB * KK * HWHW * 2); // 4.98 MB
    float* cf  = cf_part + (size_t)16 * BB * KK * CC;                   // 311 KB
    float* fil = cf + (size_t)BB * KK * CC;                             // 311 KB

    k_s1<<<1024, 256, 0, stream>>>(x, Wm, bm, mask);
    k_s2<<<1024, 256, 0, stream>>>(x, mask, cf_part);
    k_s2r<<<(BB * KK * CC + 255) / 256, 256, 0, stream>>>(cf_part, cf);
    k_filters<<<KK * 128, 256, 0, stream>>>(Wf, bf, cf, fil);
    k_s4<<<1024, 256, 0, stream>>>(x, fil, out);
}